// Round 5
// baseline (1161.995 us; speedup 1.0000x reference)
//
#include <hip/hip_runtime.h>

#define B 8
#define N 4096
#define NITER 4
#define NCH 128            // split-K chunks (b-dimension)
#define CHR 32             // rows per chunk = N/NCH
#define NCG 8              // column groups
#define CGW 512            // cols per group = N/NCG
#define TPB 256

// bf16 (stored as ushort pairs in uint) -> fp32
__device__ __forceinline__ float bf16lo(unsigned u) { return __uint_as_float(u << 16); }
__device__ __forceinline__ float bf16hi(unsigned u) { return __uint_as_float(u & 0xFFFF0000u); }

__device__ __forceinline__ unsigned short f2bf(float f) {  // RTNE
    unsigned u = __float_as_uint(f);
    return (unsigned short)((u + 0x7FFFu + ((u >> 16) & 1u)) >> 16);
}

// One-time: P fp32 -> bf16 (32 MB), zero S0/S1 and counters.
__global__ __launch_bounds__(TPB)
void pack_kernel(const float* __restrict__ P, unsigned short* __restrict__ Pbf,
                 float* __restrict__ zbase, unsigned* __restrict__ cnt) {
    const int tid = threadIdx.x;
    const size_t base = ((size_t)blockIdx.x * TPB + tid) * 16;
    const float4* src = (const float4*)(P + base);
    float4 f0 = src[0], f1 = src[1], f2 = src[2], f3 = src[3];
    unsigned w[8];
    w[0] = f2bf(f0.x) | ((unsigned)f2bf(f0.y) << 16);
    w[1] = f2bf(f0.z) | ((unsigned)f2bf(f0.w) << 16);
    w[2] = f2bf(f1.x) | ((unsigned)f2bf(f1.y) << 16);
    w[3] = f2bf(f1.z) | ((unsigned)f2bf(f1.w) << 16);
    w[4] = f2bf(f2.x) | ((unsigned)f2bf(f2.y) << 16);
    w[5] = f2bf(f2.z) | ((unsigned)f2bf(f2.w) << 16);
    w[6] = f2bf(f3.x) | ((unsigned)f2bf(f3.y) << 16);
    w[7] = f2bf(f3.z) | ((unsigned)f2bf(f3.w) << 16);
    uint4* dst = (uint4*)(Pbf + base);
    dst[0] = make_uint4(w[0], w[1], w[2], w[3]);
    dst[1] = make_uint4(w[4], w[5], w[6], w[7]);

    if (tid < 16) zbase[(size_t)blockIdx.x * 16 + tid] = 0.0f;    // S0+S1 = 65536 floats
    if (blockIdx.x == 0 && tid >= 16 && tid < 48) cnt[tid - 16] = 0u;
}

// One iteration: S[i,a] = sum_b P[b,a]*pred[i,b] via split-K atomics;
// the last block per column-group computes pred' = 1-exp(-S), clamps seeds,
// writes next pred (or d_out), and zeroes the other S buffer.
__global__ __launch_bounds__(TPB, 4)
void diffuse_iter(const unsigned short* __restrict__ Pbf,
                  const float* __restrict__ predsrc,
                  float* __restrict__ predwrite,
                  float* __restrict__ S,
                  float* __restrict__ Szero,
                  const int* __restrict__ seed_idx, int nseeds,
                  unsigned* __restrict__ cnt) {
    __shared__ __align__(16) float predLds[CHR * B];   // [b_local][i], 1 KB
    __shared__ float red[2 * 64 * 64];                 // two 16 KB reduce regions
    __shared__ int isLast;

    const int tid   = threadIdx.x;
    const int w     = tid >> 6;          // wave 0..3
    const int lane  = tid & 63;
    const int chunk = blockIdx.x;        // 0..NCH-1
    const int cg    = blockIdx.y;        // 0..NCG-1
    const int b0    = chunk * CHR;

    // stage pred chunk transposed: predLds[b_local*8 + i] (coalesced 128B runs)
    {
        const int bl = tid & 31, i = tid >> 5;
        predLds[bl * 8 + i] = predsrc[i * N + b0 + bl];
    }
    __syncthreads();

    // acc[i*8+c]: batches i, cols col0+c
    const int col0 = cg * CGW + lane * 8;
    float acc[64];
#pragma unroll
    for (int j = 0; j < 64; ++j) acc[j] = 0.0f;

    const unsigned short* pp = Pbf + (size_t)(b0 + w) * N + col0;
    const float4* prl = (const float4*)predLds;
#pragma unroll
    for (int s = 0; s < 8; ++s) {
        const int bl = s * 4 + w;                       // row = b0 + bl
        const uint4 u = *(const uint4*)(pp + (size_t)s * 4 * N);  // 8 bf16, 16B/lane
        float pc[8] = { bf16lo(u.x), bf16hi(u.x), bf16lo(u.y), bf16hi(u.y),
                        bf16lo(u.z), bf16hi(u.z), bf16lo(u.w), bf16hi(u.w) };
        const float4 pA = prl[bl * 2], pB = prl[bl * 2 + 1];  // LDS broadcast
        const float pr[8] = { pA.x, pA.y, pA.z, pA.w, pB.x, pB.y, pB.z, pB.w };
#pragma unroll
        for (int i = 0; i < 8; ++i)
#pragma unroll
            for (int c = 0; c < 8; ++c)
                acc[i * 8 + c] = fmaf(pr[i], pc[c], acc[i * 8 + c]);
    }

    // cross-wave reduce (j-major LDS layout: bank = lane%32, conflict-free b32)
    if (w == 1 || w == 3) {
        float* r = red + (w == 3 ? 4096 : 0) + lane;
#pragma unroll
        for (int j = 0; j < 64; ++j) r[j * 64] = acc[j];
    }
    __syncthreads();
    if (w == 0 || w == 2) {
        const float* r = red + (w == 2 ? 4096 : 0) + lane;
#pragma unroll
        for (int j = 0; j < 64; ++j) acc[j] += r[j * 64];
    }
    __syncthreads();
    if (w == 2) {
        float* r = red + lane;
#pragma unroll
        for (int j = 0; j < 64; ++j) r[j * 64] = acc[j];
    }
    __syncthreads();
    if (w == 0) {
        const float* r = red + lane;
#pragma unroll
        for (int j = 0; j < 64; ++j) acc[j] += r[j * 64];
        // split-K merge at the coherence point (MALL) — no fences needed for data
#pragma unroll
        for (int j = 0; j < 64; ++j)
            atomicAdd(&S[(j >> 3) * N + col0 + (j & 7)], acc[j]);
    }

    // arrive: make S-atomics globally complete, then bump the colgroup counter
    __threadfence();
    __syncthreads();
    if (tid == 0) isLast = (atomicAdd(&cnt[cg], 1u) == NCH - 1u);
    __syncthreads();
    if (!isLast) return;

    // ---- finisher: last block of this column-group ----
    __threadfence();                      // acquire: drop stale L1/L2 lines
    const int cb = cg * CGW;
    float v[16];
#pragma unroll
    for (int j = 0; j < 16; ++j) {
        const int cell = j * 256 + tid;   // 4096 cells = 8 batches x 512 cols
        const int i = cell >> 9, c = cell & 511;
        v[j] = 1.0f - __expf(-S[i * N + cb + c]);
    }
    for (int k = 0; k < nseeds; ++k) {    // clamp seeds (uniform scalar loads)
        const int nl = seed_idx[2 * k + 1] - cb;
        if ((unsigned)nl < CGW) {
            const int scell = seed_idx[2 * k] * CGW + nl;
            if ((scell & 255) == tid) v[scell >> 8] = 1.0f;
        }
    }
#pragma unroll
    for (int j = 0; j < 16; ++j) {
        const int cell = j * 256 + tid;
        const int i = cell >> 9, c = cell & 511;
        predwrite[i * N + cb + c] = v[j];
        Szero[i * N + cb + c] = 0.0f;     // pre-zero S for the iteration after next
    }
}

extern "C" void kernel_launch(void* const* d_in, const int* in_sizes, int n_in,
                              void* d_out, int out_size, void* d_ws, size_t ws_size,
                              hipStream_t stream) {
    const float* preds    = (const float*)d_in[0];   // [B, N] fp32
    const float* P        = (const float*)d_in[1];   // [N, N] fp32
    const int*   seed_idx = (const int*)d_in[2];     // [NSEEDS, 2]
    const int nseeds = in_sizes[2] / 2;
    float* out = (float*)d_out;

    unsigned short* Pbf = (unsigned short*)d_ws;     // 32 MiB
    float* fbase = (float*)(Pbf + (size_t)N * N);
    float* S0    = fbase;                 // [B][N]
    float* S1    = fbase + 32768;         // [B][N]
    float* predA = fbase + 65536;
    float* predB = fbase + 98304;
    unsigned* cnt = (unsigned*)(fbase + 131072);     // [NITER][NCG]

    pack_kernel<<<dim3((N * N) / (TPB * 16)), TPB, 0, stream>>>(P, Pbf, S0, cnt);

    const float* srcs[NITER]  = { preds, predA, predB, predA };
    float*       dsts[NITER]  = { predA, predB, predA, out   };
    float*       sbuf[NITER]  = { S0, S1, S0, S1 };
    float*       szero[NITER] = { S1, S0, S1, S0 };
    for (int it = 0; it < NITER; ++it) {
        diffuse_iter<<<dim3(NCH, NCG), TPB, 0, stream>>>(
            Pbf, srcs[it], dsts[it], sbuf[it], szero[it],
            seed_idx, nseeds, cnt + it * NCG);
    }
}

// Round 6
// 195.325 us; speedup vs baseline: 5.9490x; 5.9490x over previous
//
#include <hip/hip_runtime.h>

#define B 8
#define N 4096
#define NITER 4
#define SPLITK 128
#define R (N / SPLITK)       // 32 rows of P per chunk
#define TPB 256
#define CPT 4                // cols per thread (one float4)
#define TILEW (TPB * CPT)    // 1024 cols per block
#define COLT (N / TILEW)     // 4 column tiles
#define BN (B * N)

// partial[s][i][a] = prod_{b in chunk s} (1 - P[b,a] * pred[i,b])
__global__ __launch_bounds__(TPB)
void partial_kernel(const float* __restrict__ pred,
                    const float* __restrict__ P,
                    float* __restrict__ partial) {
    __shared__ __align__(16) float predLds[R][B];   // [b_local][batch], 1 KiB

    const int tid  = threadIdx.x;
    const int col4 = blockIdx.x * (TILEW / 4) + tid;   // this thread's float4 column index
    const int b0   = blockIdx.y * R;

    // stage pred chunk transposed (8 batches x 32 rows; coalesced 128B runs)
    predLds[tid & 31][tid >> 5] = pred[(tid >> 5) * N + b0 + (tid & 31)];
    __syncthreads();

    float acc[B][CPT];
#pragma unroll
    for (int i = 0; i < B; ++i)
#pragma unroll
        for (int c = 0; c < CPT; ++c) acc[i][c] = 1.0f;

    const float4* Pp = (const float4*)P + (size_t)b0 * (N / 4) + col4;

#pragma unroll
    for (int r = 0; r < R; ++r) {
        const float4 p4  = Pp[(size_t)r * (N / 4)];             // 16B/lane, coalesced
        const float4 prA = *(const float4*)&predLds[r][0];      // LDS broadcast
        const float4 prB = *(const float4*)&predLds[r][4];      // LDS broadcast
        const float pr[B] = { prA.x, prA.y, prA.z, prA.w, prB.x, prB.y, prB.z, prB.w };
        const float pc[CPT] = { p4.x, p4.y, p4.z, p4.w };
#pragma unroll
        for (int i = 0; i < B; ++i)
#pragma unroll
            for (int c = 0; c < CPT; ++c)
                acc[i][c] *= fmaf(-pc[c], pr[i], 1.0f);
    }

    // store: 8 coalesced float4 stores
    float4* pb = (float4*)partial + (size_t)blockIdx.y * (B * N / 4);
#pragma unroll
    for (int i = 0; i < B; ++i) {
        float4 v = { acc[i][0], acc[i][1], acc[i][2], acc[i][3] };
        pb[(size_t)i * (N / 4) + col4] = v;
    }
}

// out[i,a] = seed ? 1 : 1 - prod_s partial[s][i][a]
__global__ __launch_bounds__(TPB)
void reduce_kernel(const float* __restrict__ partial,
                   const int* __restrict__ seed_idx, int nseeds,
                   float* __restrict__ out) {
    const int idx = blockIdx.x * TPB + threadIdx.x;   // idx = i*N + a

    float q0 = 1.f, q1 = 1.f, q2 = 1.f, q3 = 1.f,
          q4 = 1.f, q5 = 1.f, q6 = 1.f, q7 = 1.f;
    const float* col = partial + idx;
#pragma unroll
    for (int s = 0; s < SPLITK; s += 8) {             // coalesced, L2/L3-hot
        q0 *= col[(size_t)(s + 0) * BN];
        q1 *= col[(size_t)(s + 1) * BN];
        q2 *= col[(size_t)(s + 2) * BN];
        q3 *= col[(size_t)(s + 3) * BN];
        q4 *= col[(size_t)(s + 4) * BN];
        q5 *= col[(size_t)(s + 5) * BN];
        q6 *= col[(size_t)(s + 6) * BN];
        q7 *= col[(size_t)(s + 7) * BN];
    }
    float v = 1.0f - (((q0 * q1) * (q2 * q3)) * ((q4 * q5) * (q6 * q7)));

    const int i = idx >> 12;        // batch
    const int a = idx & (N - 1);    // column
    for (int k = 0; k < nseeds; ++k) {   // uniform scalar loads, cheap
        if (seed_idx[2 * k] == i && seed_idx[2 * k + 1] == a) v = 1.0f;
    }
    out[idx] = v;
}

extern "C" void kernel_launch(void* const* d_in, const int* in_sizes, int n_in,
                              void* d_out, int out_size, void* d_ws, size_t ws_size,
                              hipStream_t stream) {
    const float* preds    = (const float*)d_in[0];   // [B, N]
    const float* P        = (const float*)d_in[1];   // [N, N]
    const int*   seed_idx = (const int*)d_in[2];     // [NSEEDS, 2]
    const int nseeds = in_sizes[2] / 2;
    float* out = (float*)d_out;

    float* partial = (float*)d_ws;                   // [SPLITK][B][N] = 16 MiB
    float* predA   = partial + (size_t)SPLITK * BN;  // [B][N]
    float* predB   = predA + BN;                     // [B][N]

    const float* srcs[NITER] = { preds, predA, predB, predA };
    float*       dsts[NITER] = { predA, predB, predA, out   };

    for (int it = 0; it < NITER; ++it) {
        partial_kernel<<<dim3(COLT, SPLITK), TPB, 0, stream>>>(srcs[it], P, partial);
        reduce_kernel<<<dim3(BN / TPB), TPB, 0, stream>>>(partial, seed_idx, nseeds, dsts[it]);
    }
}